// Round 10
// baseline (263.015 us; speedup 1.0000x reference)
//
#include <hip/hip_runtime.h>
#include <hip/hip_fp16.h>

// GIN forward, round 23: MERGED SCAN. Baseline R22 (256.7us ~= R20 255.8
// within noise; R9 unbundle confirmed fgg M=32 + prep-into-fill-neutral).
// Single change: scan_part_k + scan_write_k -> one scan_k (171 blocks,
// publish partial via device-scope atomic store + done-counter, spin until
// all published -- 171 blocks trivially co-resident, unlike R14's 1024-WG
// grid.sync -- then coherent atomic-load of partials and scan-write from
// register-held values). Saves one dispatch boundary + one kernel ramp +
// one 1.4MB cnt2 re-read.

#define N_NODES  50000
#define N_EDGES  600000
#define N_FEAT   64
#define DIM      128
#define N_GRAPHS 1024
#define NC       7           // src chunks: src>>13, 0..6
#define CSH      13
#define TOT2     (N_NODES * NC)          // 350000 bins
#define SCH      2048                    // scan elems per block
#define NBLK     ((TOT2 + SCH - 1) / SCH)  // 171
#define TPB      256
#define GT32     ((N_NODES + 31) / 32)     // 1563 tiles

typedef _Float16 f16x8 __attribute__((ext_vector_type(8)));
typedef float    f32x4 __attribute__((ext_vector_type(4)));

#define CNTZ2 (TOT2 / 4)                 // 87500 int4 items
#define XWORK (N_NODES * N_FEAT / 4)
#define CONV_TOTAL (XWORK + N_FEAT * DIM + 3 * DIM * DIM)
#define FILL_TOTAL (N_EDGES + CONV_TOTAL)

// ---- zero: cnt2 + done counter ----
__global__ __launch_bounds__(TPB) void zero_k(int* __restrict__ cnt2,
                                              int* __restrict__ part) {
  int i = blockIdx.x * TPB + threadIdx.x;
  if (i < CNTZ2)
    *reinterpret_cast<int4*>(cnt2 + i * 4) = make_int4(0, 0, 0, 0);
  if (i == 0) part[255] = 0;   // done counter lives at part[255]
}

// ---- histogram over (dst, src-chunk) keys; rank[e] = old count ----
__global__ __launch_bounds__(TPB) void hist_k(
    const int* __restrict__ src, const int* __restrict__ dst,
    int* __restrict__ cnt2, int* __restrict__ rank) {
  int e = blockIdx.x * TPB + threadIdx.x;
  if (e >= N_EDGES) return;
  int key = dst[e] * NC + (src[e] >> CSH);
  rank[e] = atomicAdd(&cnt2[key], 1);
}

// ---- merged scan: per-block partial -> publish -> spin-barrier ->
//      LDS scan of partials -> intra-block scan-write ----
__global__ __launch_bounds__(TPB) void scan_k(
    const int* __restrict__ cnt2, int* __restrict__ part,
    int* __restrict__ row_ptr2) {
  __shared__ int sh[4];
  __shared__ int pscan[TPB];
  __shared__ int wsum[4];
  int t = threadIdx.x, b = blockIdx.x;
  int lane = t & 63, wv = t >> 6;
  int base = b * SCH + t * 8;
  int* done = part + 255;

  // load my 8 values (kept in registers for the write phase)
  int v[8] = {0,0,0,0,0,0,0,0};
  if (base < TOT2) {    // TOT2 % 8 == 0: all 8 in-bounds together
    int4 a = *reinterpret_cast<const int4*>(cnt2 + base);
    int4 c = *reinterpret_cast<const int4*>(cnt2 + base + 4);
    v[0]=a.x; v[1]=a.y; v[2]=a.z; v[3]=a.w;
    v[4]=c.x; v[5]=c.y; v[6]=c.z; v[7]=c.w;
  }
  int ls = 0;
#pragma unroll
  for (int i = 0; i < 8; ++i) ls += v[i];

  // block partial
  int s = ls;
  for (int off = 32; off; off >>= 1) s += __shfl_down(s, off, 64);
  if (lane == 0) sh[wv] = s;
  __syncthreads();
  if (t == 0) {
    int tot = sh[0] + sh[1] + sh[2] + sh[3];
    __hip_atomic_store(&part[b], tot, __ATOMIC_RELEASE,
                       __HIP_MEMORY_SCOPE_AGENT);
    __hip_atomic_fetch_add(done, 1, __ATOMIC_ACQ_REL,
                           __HIP_MEMORY_SCOPE_AGENT);
  }
  // spin until all 171 partials are published (all blocks co-resident)
  if (t == 0) {
    while (__hip_atomic_load(done, __ATOMIC_ACQUIRE,
                             __HIP_MEMORY_SCOPE_AGENT) < NBLK) { }
  }
  __syncthreads();

  // coherent read of partials (cross-XCD safe), then LDS Hillis-Steele
  int pv = 0;
  if (t < NBLK)
    pv = __hip_atomic_load(&part[t], __ATOMIC_RELAXED,
                           __HIP_MEMORY_SCOPE_AGENT);
  pscan[t] = pv;
  __syncthreads();
  for (int off = 1; off < TPB; off <<= 1) {
    int u = (t >= off) ? pscan[t - off] : 0;
    __syncthreads();
    pscan[t] += u;
    __syncthreads();
  }
  int blk_off = (b > 0) ? pscan[b - 1] : 0;

  // intra-block exclusive scan over register-held v[8]
  int incl = ls;
  for (int off = 1; off < 64; off <<= 1) {
    int u = __shfl_up(incl, off, 64);
    if (lane >= off) incl += u;
  }
  if (lane == 63) wsum[wv] = incl;
  __syncthreads();
  int woff = 0;
  for (int w = 0; w < wv; ++w) woff += wsum[w];
  int run = blk_off + woff + (incl - ls);
  if (base < TOT2) {
    int rp[8];
#pragma unroll
    for (int i = 0; i < 8; ++i) { rp[i] = run; run += v[i]; }
    *reinterpret_cast<int4*>(row_ptr2 + base) = make_int4(rp[0], rp[1], rp[2], rp[3]);
    *reinterpret_cast<int4*>(row_ptr2 + base + 4) = make_int4(rp[4], rp[5], rp[6], rp[7]);
  }
  if (b == 0 && t == 0) row_ptr2[TOT2] = N_EDGES;
}

// ---- fill + conversion: threads < N_EDGES place edges (atomic-free,
//      pos = row_ptr2[key] + rank[e]); the rest do x->fp16 and the four
//      W transposes (streaming work hidden under fill's latency). ----
__global__ __launch_bounds__(TPB) void fill_k(
    const int* __restrict__ src, const int* __restrict__ dst,
    const int* __restrict__ row_ptr2, const int* __restrict__ rank,
    int* __restrict__ csr_src,
    const float* __restrict__ x, __half* __restrict__ xh,
    const float* __restrict__ w0, const float* __restrict__ w1,
    const float* __restrict__ w2, const float* __restrict__ w3,
    __half* __restrict__ Wt0, __half* __restrict__ Wt1,
    __half* __restrict__ Wt2, __half* __restrict__ Wt3) {
  int i = blockIdx.x * TPB + threadIdx.x;
  if (i < N_EDGES) {
    int s = src[i];
    int key = dst[i] * NC + (s >> CSH);
    csr_src[row_ptr2[key] + rank[i]] = s;
    return;
  }
  i -= N_EDGES;
  if (i < XWORK) {
    float4 v = *reinterpret_cast<const float4*>(x + (size_t)i * 4);
    union { __half2 h2[2]; uint2 u; } pk;
    pk.h2[0] = __floats2half2_rn(v.x, v.y);
    pk.h2[1] = __floats2half2_rn(v.z, v.w);
    *reinterpret_cast<uint2*>(xh + (size_t)i * 4) = pk.u;
    return;
  }
  int j = i - XWORK;
  if (j < N_FEAT * DIM) {
    int k = j >> 7, n = j & 127;
    Wt0[n * N_FEAT + k] = __float2half(w0[j]);
    return;
  }
  j -= N_FEAT * DIM;
  if (j >= 3 * DIM * DIM) return;
  int wsel = j / (DIM * DIM);
  int jj = j - wsel * (DIM * DIM);
  int k = jj >> 7, n = jj & 127;
  const float* W = (wsel == 0) ? w1 : (wsel == 1) ? w2 : w3;
  __half* Wt     = (wsel == 0) ? Wt1 : (wsel == 1) ? Wt2 : Wt3;
  Wt[n * DIM + k] = __float2half(W[jj]);
}

// ---- g64gg: per 32-row tile: gather64 -> As; h0 = relu(As@W0+b0);
//      y1 = h0@W1. B-fragments straight from L2-hot Wt. LDS 13.3KB. ----
__global__ __launch_bounds__(TPB) void g64gg_k(
    const __half* __restrict__ xh, const int* __restrict__ row_ptr2,
    const int* __restrict__ csr_src,
    const __half* __restrict__ Wt0, const float* __restrict__ b0,
    const __half* __restrict__ Wt1, __half* __restrict__ y1) {
  __shared__ __align__(16) __half As[32][72];   // gathered s tile (K=64)
  __shared__ __align__(16) __half Hs[32][136];  // h0 tile, reused as Os
  const f16x8* xv = reinterpret_cast<const f16x8*>(xh);
  int tid = threadIdx.x;
  int row0 = blockIdx.x * 32;

  // gather phase: 32 node-slots x 8 feature-lanes (64-wide)
  {
    int ns = tid >> 3, l = tid & 7;
    int node = row0 + ns;
    f16x8 o;
    if (node < N_NODES) {
      int beg = row_ptr2[node * NC];
      int end = row_ptr2[node * NC + NC];
      f16x8 self = xv[(size_t)node * 8 + l];
      float acc[8];
#pragma unroll
      for (int v = 0; v < 8; ++v) acc[v] = (float)self[v];
      int e = beg;
      for (; e + 3 < end; e += 4) {
        int s0 = csr_src[e+0], s1 = csr_src[e+1], s2 = csr_src[e+2], s3 = csr_src[e+3];
        f16x8 v0 = xv[(size_t)s0 * 8 + l];
        f16x8 v1 = xv[(size_t)s1 * 8 + l];
        f16x8 v2 = xv[(size_t)s2 * 8 + l];
        f16x8 v3 = xv[(size_t)s3 * 8 + l];
#pragma unroll
        for (int v = 0; v < 8; ++v)
          acc[v] += ((float)v0[v] + (float)v1[v]) + ((float)v2[v] + (float)v3[v]);
      }
      for (; e < end; ++e) {
        f16x8 v0 = xv[(size_t)csr_src[e] * 8 + l];
#pragma unroll
        for (int v = 0; v < 8; ++v) acc[v] += (float)v0[v];
      }
#pragma unroll
      for (int v = 0; v < 8; ++v) o[v] = (_Float16)acc[v];
    } else {
#pragma unroll
      for (int v = 0; v < 8; ++v) o[v] = (_Float16)0.f;
    }
    *reinterpret_cast<f16x8*>(&As[ns][l * 8]) = o;
  }
  __syncthreads();

  int w = tid >> 6, lane = tid & 63;
  int quad = lane >> 4, m = lane & 15;
  int col0 = w * 32;

  // phase A: h0 = relu(As @ W0 + b0)  (K=64)
  f32x4 accA[2][2];
#pragma unroll
  for (int mt = 0; mt < 2; ++mt)
#pragma unroll
    for (int nt = 0; nt < 2; ++nt) accA[mt][nt] = (f32x4){0.f,0.f,0.f,0.f};
#pragma unroll
  for (int kc = 0; kc < 2; ++kc) {
    f16x8 a0 = *reinterpret_cast<const f16x8*>(&As[m][kc*32 + quad*8]);
    f16x8 a1 = *reinterpret_cast<const f16x8*>(&As[16 + m][kc*32 + quad*8]);
#pragma unroll
    for (int nt = 0; nt < 2; ++nt) {
      f16x8 b = *reinterpret_cast<const f16x8*>(
          Wt0 + (size_t)(col0 + nt*16 + m) * N_FEAT + kc*32 + quad*8);
      accA[0][nt] = __builtin_amdgcn_mfma_f32_16x16x32_f16(a0, b, accA[0][nt], 0, 0, 0);
      accA[1][nt] = __builtin_amdgcn_mfma_f32_16x16x32_f16(a1, b, accA[1][nt], 0, 0, 0);
    }
  }
#pragma unroll
  for (int mt = 0; mt < 2; ++mt)
#pragma unroll
    for (int nt = 0; nt < 2; ++nt) {
      float bv = b0[col0 + nt*16 + m];
#pragma unroll
      for (int r = 0; r < 4; ++r)
        Hs[mt*16 + quad*4 + r][col0 + nt*16 + m] =
            __float2half(fmaxf(accA[mt][nt][r] + bv, 0.f));
    }
  __syncthreads();

  // phase B: y1 = Hs @ W1  (K=128)
  f32x4 accB[2][2];
#pragma unroll
  for (int mt = 0; mt < 2; ++mt)
#pragma unroll
    for (int nt = 0; nt < 2; ++nt) accB[mt][nt] = (f32x4){0.f,0.f,0.f,0.f};
#pragma unroll
  for (int kc = 0; kc < 4; ++kc) {
    f16x8 a0 = *reinterpret_cast<const f16x8*>(&Hs[m][kc*32 + quad*8]);
    f16x8 a1 = *reinterpret_cast<const f16x8*>(&Hs[16 + m][kc*32 + quad*8]);
#pragma unroll
    for (int nt = 0; nt < 2; ++nt) {
      f16x8 b = *reinterpret_cast<const f16x8*>(
          Wt1 + (size_t)(col0 + nt*16 + m) * DIM + kc*32 + quad*8);
      accB[0][nt] = __builtin_amdgcn_mfma_f32_16x16x32_f16(a0, b, accB[0][nt], 0, 0, 0);
      accB[1][nt] = __builtin_amdgcn_mfma_f32_16x16x32_f16(a1, b, accB[1][nt], 0, 0, 0);
    }
  }
  __syncthreads();   // Hs reads done -> reuse as Os
#pragma unroll
  for (int mt = 0; mt < 2; ++mt)
#pragma unroll
    for (int nt = 0; nt < 2; ++nt)
#pragma unroll
      for (int r = 0; r < 4; ++r)
        Hs[mt*16 + quad*4 + r][col0 + nt*16 + m] = __float2half(accB[mt][nt][r]);
  __syncthreads();
#pragma unroll
  for (int it = 0; it < 2; ++it) {
    int i = tid + it * TPB;
    int r = i >> 4, c = (i & 15) * 8;
    int row = row0 + r;
    if (row < N_NODES)
      *reinterpret_cast<f16x8*>(y1 + (size_t)row * DIM + c) =
          *reinterpret_cast<const f16x8*>(&Hs[r][c]);
  }
}

// ---- fgg (M=32, R20 shape): h' = relu(y+agg(y)+b); y' = h'@Wn ----
__global__ __launch_bounds__(TPB) void fgg_k(
    const __half* __restrict__ y, const int* __restrict__ row_ptr2,
    const int* __restrict__ csr_src, const float* __restrict__ bias,
    const __half* __restrict__ Wn, __half* __restrict__ yout) {
  __shared__ __align__(16) __half As[32][136];  // h' tile, reused as Os
  const f16x8* yv = reinterpret_cast<const f16x8*>(y);
  int tid = threadIdx.x;
  int row0 = blockIdx.x * 32;
  int g = tid >> 4, l = tid & 15;   // 16 node-slots x 16 feature-lanes

#pragma unroll 1
  for (int p = 0; p < 2; ++p) {
    int node = row0 + p * 16 + g;
    if (node < N_NODES) {
      int beg = row_ptr2[node * NC];
      int end = row_ptr2[node * NC + NC];
      f16x8 self = yv[(size_t)node * 16 + l];
      float acc[8];
#pragma unroll
      for (int v = 0; v < 8; ++v) acc[v] = (float)self[v];
      int e = beg;
      for (; e + 3 < end; e += 4) {
        int s0 = csr_src[e+0], s1 = csr_src[e+1], s2 = csr_src[e+2], s3 = csr_src[e+3];
        f16x8 v0 = yv[(size_t)s0 * 16 + l];
        f16x8 v1 = yv[(size_t)s1 * 16 + l];
        f16x8 v2 = yv[(size_t)s2 * 16 + l];
        f16x8 v3 = yv[(size_t)s3 * 16 + l];
#pragma unroll
        for (int v = 0; v < 8; ++v)
          acc[v] += ((float)v0[v] + (float)v1[v]) + ((float)v2[v] + (float)v3[v]);
      }
      for (; e < end; ++e) {
        f16x8 v0 = yv[(size_t)csr_src[e] * 16 + l];
#pragma unroll
        for (int v = 0; v < 8; ++v) acc[v] += (float)v0[v];
      }
      float4 bb0 = *reinterpret_cast<const float4*>(bias + l * 8);
      float4 bb1 = *reinterpret_cast<const float4*>(bias + l * 8 + 4);
      float bb[8] = {bb0.x, bb0.y, bb0.z, bb0.w, bb1.x, bb1.y, bb1.z, bb1.w};
      f16x8 o;
#pragma unroll
      for (int v = 0; v < 8; ++v) o[v] = (_Float16)fmaxf(acc[v] + bb[v], 0.f);
      *reinterpret_cast<f16x8*>(&As[p * 16 + g][l * 8]) = o;
    }
  }
  __syncthreads();

  int w = tid >> 6, lane = tid & 63;
  int quad = lane >> 4, m = lane & 15;
  int col0 = w * 32;
  f32x4 acc2[2][2];
#pragma unroll
  for (int mt = 0; mt < 2; ++mt)
#pragma unroll
    for (int nt = 0; nt < 2; ++nt) acc2[mt][nt] = (f32x4){0.f,0.f,0.f,0.f};
#pragma unroll
  for (int kc = 0; kc < 4; ++kc) {
    f16x8 a0 = *reinterpret_cast<const f16x8*>(&As[m][kc*32 + quad*8]);
    f16x8 a1 = *reinterpret_cast<const f16x8*>(&As[16 + m][kc*32 + quad*8]);
#pragma unroll
    for (int nt = 0; nt < 2; ++nt) {
      f16x8 b = *reinterpret_cast<const f16x8*>(
          Wn + (size_t)(col0 + nt*16 + m) * DIM + kc*32 + quad*8);
      acc2[0][nt] = __builtin_amdgcn_mfma_f32_16x16x32_f16(a0, b, acc2[0][nt], 0, 0, 0);
      acc2[1][nt] = __builtin_amdgcn_mfma_f32_16x16x32_f16(a1, b, acc2[1][nt], 0, 0, 0);
    }
  }
  __syncthreads();   // As reads done -> reuse as Os
#pragma unroll
  for (int mt = 0; mt < 2; ++mt)
#pragma unroll
    for (int nt = 0; nt < 2; ++nt)
#pragma unroll
      for (int r = 0; r < 4; ++r)
        As[mt*16 + quad*4 + r][col0 + nt*16 + m] = __float2half(acc2[mt][nt][r]);
  __syncthreads();
#pragma unroll
  for (int it = 0; it < 2; ++it) {
    int i = tid + it * TPB;
    int r = i >> 4, c = (i & 15) * 8;
    int row = row0 + r;
    if (row < N_NODES)
      *reinterpret_cast<f16x8*>(yout + (size_t)row * DIM + c) =
          *reinterpret_cast<const f16x8*>(&As[r][c]);
  }
}

// ---- standalone gather (R13 shape): 16 lanes/node, 4-deep unroll ----
template<int F, bool BR>
__global__ __launch_bounds__(TPB) void gather_k(
    const __half* __restrict__ y, const int* __restrict__ row_ptr2,
    const int* __restrict__ csr_src, const float* __restrict__ bias,
    __half* __restrict__ hout) {
  constexpr int CH = F / 8;
  const f16x8* yv = reinterpret_cast<const f16x8*>(y);
  int gid  = blockIdx.x * TPB + threadIdx.x;
  int node = gid / CH;
  int l    = gid % CH;
  if (node >= N_NODES) return;
  int beg = row_ptr2[node * NC];
  int end = row_ptr2[node * NC + NC];

  f16x8 self = yv[(size_t)node * CH + l];
  float acc[8];
#pragma unroll
  for (int v = 0; v < 8; ++v) acc[v] = (float)self[v];

  int e = beg;
  for (; e + 3 < end; e += 4) {
    int s0 = csr_src[e+0], s1 = csr_src[e+1], s2 = csr_src[e+2], s3 = csr_src[e+3];
    f16x8 v0 = yv[(size_t)s0 * CH + l];
    f16x8 v1 = yv[(size_t)s1 * CH + l];
    f16x8 v2 = yv[(size_t)s2 * CH + l];
    f16x8 v3 = yv[(size_t)s3 * CH + l];
#pragma unroll
    for (int v = 0; v < 8; ++v)
      acc[v] += ((float)v0[v] + (float)v1[v]) + ((float)v2[v] + (float)v3[v]);
  }
  for (; e < end; ++e) {
    f16x8 v0 = yv[(size_t)csr_src[e] * CH + l];
#pragma unroll
    for (int v = 0; v < 8; ++v) acc[v] += (float)v0[v];
  }

  f16x8 o;
  if (BR) {
    float4 b0 = *reinterpret_cast<const float4*>(bias + l * 8);
    float4 b1 = *reinterpret_cast<const float4*>(bias + l * 8 + 4);
    float bb[8] = {b0.x, b0.y, b0.z, b0.w, b1.x, b1.y, b1.z, b1.w};
#pragma unroll
    for (int v = 0; v < 8; ++v) o[v] = (_Float16)fmaxf(acc[v] + bb[v], 0.f);
  } else {
#pragma unroll
    for (int v = 0; v < 8; ++v) o[v] = (_Float16)acc[v];
  }
  reinterpret_cast<f16x8*>(hout)[(size_t)node * CH + l] = o;
}

// ---- fused mean-pool (sorted batch) + post-MLP (fp32) ----
__global__ __launch_bounds__(128) void pool_post_k(
    const __half* __restrict__ h, const int* __restrict__ batch,
    const float* __restrict__ W, const float* __restrict__ bias,
    float* __restrict__ out) {
  __shared__ float xs[DIM];
  int g = blockIdx.x;
  int col = threadIdx.x;
  int lo = 0, hi = N_NODES;
  while (lo < hi) { int mid = (lo + hi) >> 1; if (batch[mid] < g) lo = mid + 1; else hi = mid; }
  int beg = lo;
  hi = N_NODES;
  while (lo < hi) { int mid = (lo + hi) >> 1; if (batch[mid] < g + 1) lo = mid + 1; else hi = mid; }
  int end = lo;

  float acc = 0.f;
  for (int n = beg; n < end; ++n) acc += __half2float(h[(size_t)n * DIM + col]);
  float cnt = fmaxf((float)(end - beg), 1.0f);
  xs[col] = acc / cnt;
  __syncthreads();
  float o = bias[col];
  for (int k = 0; k < DIM; ++k)
    o = fmaf(xs[k], W[(size_t)k * DIM + col], o);
  out[(size_t)g * DIM + col] = fmaxf(o, 0.f);
}

extern "C" void kernel_launch(void* const* d_in, const int* in_sizes, int n_in,
                              void* d_out, int out_size, void* d_ws, size_t ws_size,
                              hipStream_t stream) {
  const float* x    = (const float*)d_in[0];
  const int*   ei   = (const int*)d_in[1];
  const int*   batch= (const int*)d_in[2];
  const float* w0 = (const float*)d_in[3];  const float* b0 = (const float*)d_in[4];
  const float* w1 = (const float*)d_in[5];  const float* b1 = (const float*)d_in[6];
  const float* w2 = (const float*)d_in[7];  const float* b2 = (const float*)d_in[8];
  const float* w3 = (const float*)d_in[9];  const float* b3 = (const float*)d_in[10];
  const float* wp = (const float*)d_in[11]; const float* bp = (const float*)d_in[12];
  float* out = (float*)d_out;

  const int* src = ei;
  const int* dst = ei + N_EDGES;

  __half* xh = (__half*)d_ws;
  __half* yA = xh + (size_t)N_NODES * N_FEAT;         // y1, then y3
  __half* yB = yA + (size_t)N_NODES * DIM;            // y2
  __half* h  = yB + (size_t)N_NODES * DIM;            // final h3
  __half* Wt0 = h + (size_t)N_NODES * DIM;
  __half* Wt1 = Wt0 + N_FEAT * DIM;
  __half* Wt2 = Wt1 + DIM * DIM;
  __half* Wt3 = Wt2 + DIM * DIM;
  int* cnt2     = (int*)(Wt3 + DIM * DIM);
  int* rank     = cnt2 + TOT2;
  int* part     = rank + N_EDGES;
  int* row_ptr2 = part + 256;
  int* csr_src  = row_ptr2 + (TOT2 + 1);

  // ---- CSR build (merged scan; rank-based fill + hidden conversion) ----
  zero_k<<<(CNTZ2 + TPB - 1) / TPB, TPB, 0, stream>>>(cnt2, part);
  hist_k<<<(N_EDGES + TPB - 1) / TPB, TPB, 0, stream>>>(src, dst, cnt2, rank);
  scan_k<<<NBLK, TPB, 0, stream>>>(cnt2, part, row_ptr2);
  fill_k<<<(FILL_TOTAL + TPB - 1) / TPB, TPB, 0, stream>>>(
      src, dst, row_ptr2, rank, csr_src,
      x, xh, w0, w1, w2, w3, Wt0, Wt1, Wt2, Wt3);

  // ---- layer 0+1 fused: gather64 -> h0 = relu(.@W0+b0) -> y1 = h0@W1 ----
  g64gg_k<<<GT32, TPB, 0, stream>>>(xh, row_ptr2, csr_src, Wt0, b0, Wt1, yA);

  // ---- fused gather+gemm (M=32): y1 -> y2, y2 -> y3 ----
  fgg_k<<<GT32, TPB, 0, stream>>>(yA, row_ptr2, csr_src, b1, Wt2, yB);
  fgg_k<<<GT32, TPB, 0, stream>>>(yB, row_ptr2, csr_src, b2, Wt3, yA);

  // ---- final gather: h3 = relu(y3 + agg(y3) + b3) ----
  gather_k<DIM, true><<<(N_NODES * 16 + TPB - 1) / TPB, TPB, 0, stream>>>(
      yA, row_ptr2, csr_src, b3, h);

  // ---- pool + post-MLP ----
  pool_post_k<<<N_GRAPHS, 128, 0, stream>>>(h, batch, wp, bp, out);
}

// Round 11
// 254.356 us; speedup vs baseline: 1.0340x; 1.0340x over previous
//
#include <hip/hip_runtime.h>
#include <hip/hip_fp16.h>

// GIN forward, round 24: TAIL FUSION, SCAN REVERTED. R23's merged scan
// regressed (263 vs 256.7: spin-barrier costlier than the dispatch
// boundary it saved) -> split scan restored (exact R22 build).
// New single variable: final gather + mean-pool fused WITHOUT atomics
// (R19 lesson): gpp_k = 4 blocks/graph (4096 blocks = full load
// concurrency), each gathers its node subset (16 lanes/node, proven wave
// shape), LDS-reduces to partial[graph][part][128] (written once, no
// atomics, no zeroing); post_k sums 4 partials + post-MLP. Deletes the
// h buffer and its 25.6MB round trip; dispatch count unchanged.

#define N_NODES  50000
#define N_EDGES  600000
#define N_FEAT   64
#define DIM      128
#define N_GRAPHS 1024
#define NC       7           // src chunks: src>>13, 0..6
#define CSH      13
#define TOT2     (N_NODES * NC)          // 350000 bins
#define SCH      2048                    // scan elems per block
#define NBLK     ((TOT2 + SCH - 1) / SCH)  // 171
#define TPB      256
#define GT32     ((N_NODES + 31) / 32)     // 1563 tiles
#define GSPLIT   4                         // pool parts per graph

typedef _Float16 f16x8 __attribute__((ext_vector_type(8)));
typedef float    f32x4 __attribute__((ext_vector_type(4)));

#define CNTZ2 (TOT2 / 4)                 // 87500 int4 items
#define XWORK (N_NODES * N_FEAT / 4)
#define CONV_TOTAL (XWORK + N_FEAT * DIM + 3 * DIM * DIM)
#define FILL_TOTAL (N_EDGES + CONV_TOTAL)

// ---- zero: cnt2 only ----
__global__ __launch_bounds__(TPB) void zero_k(int* __restrict__ cnt2) {
  int i = blockIdx.x * TPB + threadIdx.x;
  if (i < CNTZ2)
    *reinterpret_cast<int4*>(cnt2 + i * 4) = make_int4(0, 0, 0, 0);
}

// ---- histogram over (dst, src-chunk) keys; rank[e] = old count ----
__global__ __launch_bounds__(TPB) void hist_k(
    const int* __restrict__ src, const int* __restrict__ dst,
    int* __restrict__ cnt2, int* __restrict__ rank) {
  int e = blockIdx.x * TPB + threadIdx.x;
  if (e >= N_EDGES) return;
  int key = dst[e] * NC + (src[e] >> CSH);
  rank[e] = atomicAdd(&cnt2[key], 1);
}

// ---- scan phase 1: per-block (2048 elems) partial sums ----
__global__ __launch_bounds__(TPB) void scan_part_k(
    const int* __restrict__ cnt2, int* __restrict__ part) {
  __shared__ int ws[4];
  int t = threadIdx.x, b = blockIdx.x;
  int base = b * SCH + t * 8;
  int s = 0;
  if (base < TOT2) {    // TOT2 % 8 == 0: all 8 in-bounds together
    int4 a = *reinterpret_cast<const int4*>(cnt2 + base);
    int4 c = *reinterpret_cast<const int4*>(cnt2 + base + 4);
    s = a.x + a.y + a.z + a.w + c.x + c.y + c.z + c.w;
  }
  for (int off = 32; off; off >>= 1) s += __shfl_down(s, off, 64);
  int lane = t & 63, wv = t >> 6;
  if (lane == 0) ws[wv] = s;
  __syncthreads();
  if (t == 0) part[b] = ws[0] + ws[1] + ws[2] + ws[3];
}

// ---- scan phase 2: LDS scan of NBLK partials + intra-block scan-write ----
__global__ __launch_bounds__(TPB) void scan_write_k(
    const int* __restrict__ cnt2, const int* __restrict__ part,
    int* __restrict__ row_ptr2) {
  __shared__ int pscan[TPB];
  __shared__ int wsum[4];
  int t = threadIdx.x, b = blockIdx.x;
  int lane = t & 63, wv = t >> 6;
  int base = b * SCH + t * 8;

  pscan[t] = (t < NBLK) ? part[t] : 0;
  __syncthreads();
  for (int off = 1; off < TPB; off <<= 1) {
    int v = (t >= off) ? pscan[t - off] : 0;
    __syncthreads();
    pscan[t] += v;
    __syncthreads();
  }
  int blk_off = (b > 0) ? pscan[b - 1] : 0;

  int v[8] = {0,0,0,0,0,0,0,0};
  if (base < TOT2) {
    int4 a = *reinterpret_cast<const int4*>(cnt2 + base);
    int4 c = *reinterpret_cast<const int4*>(cnt2 + base + 4);
    v[0]=a.x; v[1]=a.y; v[2]=a.z; v[3]=a.w;
    v[4]=c.x; v[5]=c.y; v[6]=c.z; v[7]=c.w;
  }
  int ls = 0;
#pragma unroll
  for (int i = 0; i < 8; ++i) ls += v[i];
  int incl = ls;
  for (int off = 1; off < 64; off <<= 1) {
    int u = __shfl_up(incl, off, 64);
    if (lane >= off) incl += u;
  }
  if (lane == 63) wsum[wv] = incl;
  __syncthreads();
  int woff = 0;
  for (int w = 0; w < wv; ++w) woff += wsum[w];
  int run = blk_off + woff + (incl - ls);
  if (base < TOT2) {
    int rp[8];
#pragma unroll
    for (int i = 0; i < 8; ++i) { rp[i] = run; run += v[i]; }
    *reinterpret_cast<int4*>(row_ptr2 + base) = make_int4(rp[0], rp[1], rp[2], rp[3]);
    *reinterpret_cast<int4*>(row_ptr2 + base + 4) = make_int4(rp[4], rp[5], rp[6], rp[7]);
  }
  if (b == 0 && t == 0) row_ptr2[TOT2] = N_EDGES;
}

// ---- fill + conversion: threads < N_EDGES place edges (atomic-free,
//      pos = row_ptr2[key] + rank[e]); the rest do x->fp16 and the four
//      W transposes (streaming work hidden under fill's latency). ----
__global__ __launch_bounds__(TPB) void fill_k(
    const int* __restrict__ src, const int* __restrict__ dst,
    const int* __restrict__ row_ptr2, const int* __restrict__ rank,
    int* __restrict__ csr_src,
    const float* __restrict__ x, __half* __restrict__ xh,
    const float* __restrict__ w0, const float* __restrict__ w1,
    const float* __restrict__ w2, const float* __restrict__ w3,
    __half* __restrict__ Wt0, __half* __restrict__ Wt1,
    __half* __restrict__ Wt2, __half* __restrict__ Wt3) {
  int i = blockIdx.x * TPB + threadIdx.x;
  if (i < N_EDGES) {
    int s = src[i];
    int key = dst[i] * NC + (s >> CSH);
    csr_src[row_ptr2[key] + rank[i]] = s;
    return;
  }
  i -= N_EDGES;
  if (i < XWORK) {
    float4 v = *reinterpret_cast<const float4*>(x + (size_t)i * 4);
    union { __half2 h2[2]; uint2 u; } pk;
    pk.h2[0] = __floats2half2_rn(v.x, v.y);
    pk.h2[1] = __floats2half2_rn(v.z, v.w);
    *reinterpret_cast<uint2*>(xh + (size_t)i * 4) = pk.u;
    return;
  }
  int j = i - XWORK;
  if (j < N_FEAT * DIM) {
    int k = j >> 7, n = j & 127;
    Wt0[n * N_FEAT + k] = __float2half(w0[j]);
    return;
  }
  j -= N_FEAT * DIM;
  if (j >= 3 * DIM * DIM) return;
  int wsel = j / (DIM * DIM);
  int jj = j - wsel * (DIM * DIM);
  int k = jj >> 7, n = jj & 127;
  const float* W = (wsel == 0) ? w1 : (wsel == 1) ? w2 : w3;
  __half* Wt     = (wsel == 0) ? Wt1 : (wsel == 1) ? Wt2 : Wt3;
  Wt[n * DIM + k] = __float2half(W[jj]);
}

// ---- g64gg: per 32-row tile: gather64 -> As; h0 = relu(As@W0+b0);
//      y1 = h0@W1. B-fragments straight from L2-hot Wt. LDS 13.3KB. ----
__global__ __launch_bounds__(TPB) void g64gg_k(
    const __half* __restrict__ xh, const int* __restrict__ row_ptr2,
    const int* __restrict__ csr_src,
    const __half* __restrict__ Wt0, const float* __restrict__ b0,
    const __half* __restrict__ Wt1, __half* __restrict__ y1) {
  __shared__ __align__(16) __half As[32][72];   // gathered s tile (K=64)
  __shared__ __align__(16) __half Hs[32][136];  // h0 tile, reused as Os
  const f16x8* xv = reinterpret_cast<const f16x8*>(xh);
  int tid = threadIdx.x;
  int row0 = blockIdx.x * 32;

  // gather phase: 32 node-slots x 8 feature-lanes (64-wide)
  {
    int ns = tid >> 3, l = tid & 7;
    int node = row0 + ns;
    f16x8 o;
    if (node < N_NODES) {
      int beg = row_ptr2[node * NC];
      int end = row_ptr2[node * NC + NC];
      f16x8 self = xv[(size_t)node * 8 + l];
      float acc[8];
#pragma unroll
      for (int v = 0; v < 8; ++v) acc[v] = (float)self[v];
      int e = beg;
      for (; e + 3 < end; e += 4) {
        int s0 = csr_src[e+0], s1 = csr_src[e+1], s2 = csr_src[e+2], s3 = csr_src[e+3];
        f16x8 v0 = xv[(size_t)s0 * 8 + l];
        f16x8 v1 = xv[(size_t)s1 * 8 + l];
        f16x8 v2 = xv[(size_t)s2 * 8 + l];
        f16x8 v3 = xv[(size_t)s3 * 8 + l];
#pragma unroll
        for (int v = 0; v < 8; ++v)
          acc[v] += ((float)v0[v] + (float)v1[v]) + ((float)v2[v] + (float)v3[v]);
      }
      for (; e < end; ++e) {
        f16x8 v0 = xv[(size_t)csr_src[e] * 8 + l];
#pragma unroll
        for (int v = 0; v < 8; ++v) acc[v] += (float)v0[v];
      }
#pragma unroll
      for (int v = 0; v < 8; ++v) o[v] = (_Float16)acc[v];
    } else {
#pragma unroll
      for (int v = 0; v < 8; ++v) o[v] = (_Float16)0.f;
    }
    *reinterpret_cast<f16x8*>(&As[ns][l * 8]) = o;
  }
  __syncthreads();

  int w = tid >> 6, lane = tid & 63;
  int quad = lane >> 4, m = lane & 15;
  int col0 = w * 32;

  // phase A: h0 = relu(As @ W0 + b0)  (K=64)
  f32x4 accA[2][2];
#pragma unroll
  for (int mt = 0; mt < 2; ++mt)
#pragma unroll
    for (int nt = 0; nt < 2; ++nt) accA[mt][nt] = (f32x4){0.f,0.f,0.f,0.f};
#pragma unroll
  for (int kc = 0; kc < 2; ++kc) {
    f16x8 a0 = *reinterpret_cast<const f16x8*>(&As[m][kc*32 + quad*8]);
    f16x8 a1 = *reinterpret_cast<const f16x8*>(&As[16 + m][kc*32 + quad*8]);
#pragma unroll
    for (int nt = 0; nt < 2; ++nt) {
      f16x8 b = *reinterpret_cast<const f16x8*>(
          Wt0 + (size_t)(col0 + nt*16 + m) * N_FEAT + kc*32 + quad*8);
      accA[0][nt] = __builtin_amdgcn_mfma_f32_16x16x32_f16(a0, b, accA[0][nt], 0, 0, 0);
      accA[1][nt] = __builtin_amdgcn_mfma_f32_16x16x32_f16(a1, b, accA[1][nt], 0, 0, 0);
    }
  }
#pragma unroll
  for (int mt = 0; mt < 2; ++mt)
#pragma unroll
    for (int nt = 0; nt < 2; ++nt) {
      float bv = b0[col0 + nt*16 + m];
#pragma unroll
      for (int r = 0; r < 4; ++r)
        Hs[mt*16 + quad*4 + r][col0 + nt*16 + m] =
            __float2half(fmaxf(accA[mt][nt][r] + bv, 0.f));
    }
  __syncthreads();

  // phase B: y1 = Hs @ W1  (K=128)
  f32x4 accB[2][2];
#pragma unroll
  for (int mt = 0; mt < 2; ++mt)
#pragma unroll
    for (int nt = 0; nt < 2; ++nt) accB[mt][nt] = (f32x4){0.f,0.f,0.f,0.f};
#pragma unroll
  for (int kc = 0; kc < 4; ++kc) {
    f16x8 a0 = *reinterpret_cast<const f16x8*>(&Hs[m][kc*32 + quad*8]);
    f16x8 a1 = *reinterpret_cast<const f16x8*>(&Hs[16 + m][kc*32 + quad*8]);
#pragma unroll
    for (int nt = 0; nt < 2; ++nt) {
      f16x8 b = *reinterpret_cast<const f16x8*>(
          Wt1 + (size_t)(col0 + nt*16 + m) * DIM + kc*32 + quad*8);
      accB[0][nt] = __builtin_amdgcn_mfma_f32_16x16x32_f16(a0, b, accB[0][nt], 0, 0, 0);
      accB[1][nt] = __builtin_amdgcn_mfma_f32_16x16x32_f16(a1, b, accB[1][nt], 0, 0, 0);
    }
  }
  __syncthreads();   // Hs reads done -> reuse as Os
#pragma unroll
  for (int mt = 0; mt < 2; ++mt)
#pragma unroll
    for (int nt = 0; nt < 2; ++nt)
#pragma unroll
      for (int r = 0; r < 4; ++r)
        Hs[mt*16 + quad*4 + r][col0 + nt*16 + m] = __float2half(accB[mt][nt][r]);
  __syncthreads();
#pragma unroll
  for (int it = 0; it < 2; ++it) {
    int i = tid + it * TPB;
    int r = i >> 4, c = (i & 15) * 8;
    int row = row0 + r;
    if (row < N_NODES)
      *reinterpret_cast<f16x8*>(y1 + (size_t)row * DIM + c) =
          *reinterpret_cast<const f16x8*>(&Hs[r][c]);
  }
}

// ---- fgg (M=32, R20 shape): h' = relu(y+agg(y)+b); y' = h'@Wn ----
__global__ __launch_bounds__(TPB) void fgg_k(
    const __half* __restrict__ y, const int* __restrict__ row_ptr2,
    const int* __restrict__ csr_src, const float* __restrict__ bias,
    const __half* __restrict__ Wn, __half* __restrict__ yout) {
  __shared__ __align__(16) __half As[32][136];  // h' tile, reused as Os
  const f16x8* yv = reinterpret_cast<const f16x8*>(y);
  int tid = threadIdx.x;
  int row0 = blockIdx.x * 32;
  int g = tid >> 4, l = tid & 15;   // 16 node-slots x 16 feature-lanes

#pragma unroll 1
  for (int p = 0; p < 2; ++p) {
    int node = row0 + p * 16 + g;
    if (node < N_NODES) {
      int beg = row_ptr2[node * NC];
      int end = row_ptr2[node * NC + NC];
      f16x8 self = yv[(size_t)node * 16 + l];
      float acc[8];
#pragma unroll
      for (int v = 0; v < 8; ++v) acc[v] = (float)self[v];
      int e = beg;
      for (; e + 3 < end; e += 4) {
        int s0 = csr_src[e+0], s1 = csr_src[e+1], s2 = csr_src[e+2], s3 = csr_src[e+3];
        f16x8 v0 = yv[(size_t)s0 * 16 + l];
        f16x8 v1 = yv[(size_t)s1 * 16 + l];
        f16x8 v2 = yv[(size_t)s2 * 16 + l];
        f16x8 v3 = yv[(size_t)s3 * 16 + l];
#pragma unroll
        for (int v = 0; v < 8; ++v)
          acc[v] += ((float)v0[v] + (float)v1[v]) + ((float)v2[v] + (float)v3[v]);
      }
      for (; e < end; ++e) {
        f16x8 v0 = yv[(size_t)csr_src[e] * 16 + l];
#pragma unroll
        for (int v = 0; v < 8; ++v) acc[v] += (float)v0[v];
      }
      float4 bb0 = *reinterpret_cast<const float4*>(bias + l * 8);
      float4 bb1 = *reinterpret_cast<const float4*>(bias + l * 8 + 4);
      float bb[8] = {bb0.x, bb0.y, bb0.z, bb0.w, bb1.x, bb1.y, bb1.z, bb1.w};
      f16x8 o;
#pragma unroll
      for (int v = 0; v < 8; ++v) o[v] = (_Float16)fmaxf(acc[v] + bb[v], 0.f);
      *reinterpret_cast<f16x8*>(&As[p * 16 + g][l * 8]) = o;
    }
  }
  __syncthreads();

  int w = tid >> 6, lane = tid & 63;
  int quad = lane >> 4, m = lane & 15;
  int col0 = w * 32;
  f32x4 acc2[2][2];
#pragma unroll
  for (int mt = 0; mt < 2; ++mt)
#pragma unroll
    for (int nt = 0; nt < 2; ++nt) acc2[mt][nt] = (f32x4){0.f,0.f,0.f,0.f};
#pragma unroll
  for (int kc = 0; kc < 4; ++kc) {
    f16x8 a0 = *reinterpret_cast<const f16x8*>(&As[m][kc*32 + quad*8]);
    f16x8 a1 = *reinterpret_cast<const f16x8*>(&As[16 + m][kc*32 + quad*8]);
#pragma unroll
    for (int nt = 0; nt < 2; ++nt) {
      f16x8 b = *reinterpret_cast<const f16x8*>(
          Wn + (size_t)(col0 + nt*16 + m) * DIM + kc*32 + quad*8);
      acc2[0][nt] = __builtin_amdgcn_mfma_f32_16x16x32_f16(a0, b, acc2[0][nt], 0, 0, 0);
      acc2[1][nt] = __builtin_amdgcn_mfma_f32_16x16x32_f16(a1, b, acc2[1][nt], 0, 0, 0);
    }
  }
  __syncthreads();   // As reads done -> reuse as Os
#pragma unroll
  for (int mt = 0; mt < 2; ++mt)
#pragma unroll
    for (int nt = 0; nt < 2; ++nt)
#pragma unroll
      for (int r = 0; r < 4; ++r)
        As[mt*16 + quad*4 + r][col0 + nt*16 + m] = __float2half(acc2[mt][nt][r]);
  __syncthreads();
#pragma unroll
  for (int it = 0; it < 2; ++it) {
    int i = tid + it * TPB;
    int r = i >> 4, c = (i & 15) * 8;
    int row = row0 + r;
    if (row < N_NODES)
      *reinterpret_cast<f16x8*>(yout + (size_t)row * DIM + c) =
          *reinterpret_cast<const f16x8*>(&As[r][c]);
  }
}

// ---- gpp: final gather + relu + per-part pool sum (no atomics).
// 4 blocks per graph; block (g,p) handles node indices i%4==p via
// 16 node-slots x 16 feature-lanes; LDS-reduce across slots; one
// write per (g,p,col). ----
__global__ __launch_bounds__(TPB) void gpp_k(
    const __half* __restrict__ y, const int* __restrict__ row_ptr2,
    const int* __restrict__ csr_src, const float* __restrict__ bias,
    const int* __restrict__ batch, float* __restrict__ partial) {
  __shared__ float red[16][DIM];   // 8KB
  const f16x8* yv = reinterpret_cast<const f16x8*>(y);
  int g = blockIdx.x >> 2, p = blockIdx.x & 3;
  int t = threadIdx.x;
  int s = t >> 4, l = t & 15;

  int lo = 0, hi = N_NODES;
  while (lo < hi) { int mid = (lo + hi) >> 1; if (batch[mid] < g) lo = mid + 1; else hi = mid; }
  int beg = lo;
  hi = N_NODES;
  while (lo < hi) { int mid = (lo + hi) >> 1; if (batch[mid] < g + 1) lo = mid + 1; else hi = mid; }
  int end = lo;

  float4 bb0 = *reinterpret_cast<const float4*>(bias + l * 8);
  float4 bb1 = *reinterpret_cast<const float4*>(bias + l * 8 + 4);
  float bb[8] = {bb0.x, bb0.y, bb0.z, bb0.w, bb1.x, bb1.y, bb1.z, bb1.w};

  float pacc[8];
#pragma unroll
  for (int v = 0; v < 8; ++v) pacc[v] = 0.f;

  for (int i = p + GSPLIT * s; beg + i < end; i += GSPLIT * 16) {
    int node = beg + i;
    int eb = row_ptr2[node * NC];
    int ee = row_ptr2[node * NC + NC];
    f16x8 self = yv[(size_t)node * 16 + l];
    float acc[8];
#pragma unroll
    for (int v = 0; v < 8; ++v) acc[v] = (float)self[v];
    int e = eb;
    for (; e + 3 < ee; e += 4) {
      int s0 = csr_src[e+0], s1 = csr_src[e+1], s2 = csr_src[e+2], s3 = csr_src[e+3];
      f16x8 v0 = yv[(size_t)s0 * 16 + l];
      f16x8 v1 = yv[(size_t)s1 * 16 + l];
      f16x8 v2 = yv[(size_t)s2 * 16 + l];
      f16x8 v3 = yv[(size_t)s3 * 16 + l];
#pragma unroll
      for (int v = 0; v < 8; ++v)
        acc[v] += ((float)v0[v] + (float)v1[v]) + ((float)v2[v] + (float)v3[v]);
    }
    for (; e < ee; ++e) {
      f16x8 v0 = yv[(size_t)csr_src[e] * 16 + l];
#pragma unroll
      for (int v = 0; v < 8; ++v) acc[v] += (float)v0[v];
    }
#pragma unroll
    for (int v = 0; v < 8; ++v) pacc[v] += fmaxf(acc[v] + bb[v], 0.f);
  }

#pragma unroll
  for (int v = 0; v < 8; ++v) red[s][l * 8 + v] = pacc[v];
  __syncthreads();
  if (t < DIM) {
    float sum = 0.f;
#pragma unroll
    for (int ss = 0; ss < 16; ++ss) sum += red[ss][t];
    partial[((size_t)g * GSPLIT + p) * DIM + t] = sum;
  }
}

// ---- post: pooled = sum(partials)/cnt ; out = relu(pooled@Wp + bp) ----
__global__ __launch_bounds__(128) void post_k(
    const float* __restrict__ partial, const int* __restrict__ batch,
    const float* __restrict__ W, const float* __restrict__ bias,
    float* __restrict__ out) {
  __shared__ float xs[DIM];
  int g = blockIdx.x;
  int col = threadIdx.x;
  int lo = 0, hi = N_NODES;
  while (lo < hi) { int mid = (lo + hi) >> 1; if (batch[mid] < g) lo = mid + 1; else hi = mid; }
  int beg = lo;
  hi = N_NODES;
  while (lo < hi) { int mid = (lo + hi) >> 1; if (batch[mid] < g + 1) lo = mid + 1; else hi = mid; }
  int end = lo;

  float cnt = fmaxf((float)(end - beg), 1.0f);
  float sum = 0.f;
#pragma unroll
  for (int p = 0; p < GSPLIT; ++p)
    sum += partial[((size_t)g * GSPLIT + p) * DIM + col];
  xs[col] = sum / cnt;
  __syncthreads();
  float o = bias[col];
  for (int k = 0; k < DIM; ++k)
    o = fmaf(xs[k], W[(size_t)k * DIM + col], o);
  out[(size_t)g * DIM + col] = fmaxf(o, 0.f);
}

extern "C" void kernel_launch(void* const* d_in, const int* in_sizes, int n_in,
                              void* d_out, int out_size, void* d_ws, size_t ws_size,
                              hipStream_t stream) {
  const float* x    = (const float*)d_in[0];
  const int*   ei   = (const int*)d_in[1];
  const int*   batch= (const int*)d_in[2];
  const float* w0 = (const float*)d_in[3];  const float* b0 = (const float*)d_in[4];
  const float* w1 = (const float*)d_in[5];  const float* b1 = (const float*)d_in[6];
  const float* w2 = (const float*)d_in[7];  const float* b2 = (const float*)d_in[8];
  const float* w3 = (const float*)d_in[9];  const float* b3 = (const float*)d_in[10];
  const float* wp = (const float*)d_in[11]; const float* bp = (const float*)d_in[12];
  float* out = (float*)d_out;

  const int* src = ei;
  const int* dst = ei + N_EDGES;

  __half* xh = (__half*)d_ws;
  __half* yA = xh + (size_t)N_NODES * N_FEAT;         // y1, then y3
  __half* yB = yA + (size_t)N_NODES * DIM;            // y2
  __half* Wt0 = yB + (size_t)N_NODES * DIM;
  __half* Wt1 = Wt0 + N_FEAT * DIM;
  __half* Wt2 = Wt1 + DIM * DIM;
  __half* Wt3 = Wt2 + DIM * DIM;
  float* partial = (float*)(Wt3 + DIM * DIM);         // 4*1024*128 f32 = 2MB
  int* cnt2     = (int*)(partial + (size_t)N_GRAPHS * GSPLIT * DIM);
  int* rank     = cnt2 + TOT2;
  int* part     = rank + N_EDGES;
  int* row_ptr2 = part + 256;
  int* csr_src  = row_ptr2 + (TOT2 + 1);

  // ---- CSR build (split scan; rank-based fill + hidden conversion) ----
  zero_k<<<(CNTZ2 + TPB - 1) / TPB, TPB, 0, stream>>>(cnt2);
  hist_k<<<(N_EDGES + TPB - 1) / TPB, TPB, 0, stream>>>(src, dst, cnt2, rank);
  scan_part_k <<<NBLK, TPB, 0, stream>>>(cnt2, part);
  scan_write_k<<<NBLK, TPB, 0, stream>>>(cnt2, part, row_ptr2);
  fill_k<<<(FILL_TOTAL + TPB - 1) / TPB, TPB, 0, stream>>>(
      src, dst, row_ptr2, rank, csr_src,
      x, xh, w0, w1, w2, w3, Wt0, Wt1, Wt2, Wt3);

  // ---- layer 0+1 fused: gather64 -> h0 = relu(.@W0+b0) -> y1 = h0@W1 ----
  g64gg_k<<<GT32, TPB, 0, stream>>>(xh, row_ptr2, csr_src, Wt0, b0, Wt1, yA);

  // ---- fused gather+gemm (M=32): y1 -> y2, y2 -> y3 ----
  fgg_k<<<GT32, TPB, 0, stream>>>(yA, row_ptr2, csr_src, b1, Wt2, yB);
  fgg_k<<<GT32, TPB, 0, stream>>>(yB, row_ptr2, csr_src, b2, Wt3, yA);

  // ---- final gather + per-part pool sums (no atomics), then post ----
  gpp_k<<<N_GRAPHS * GSPLIT, TPB, 0, stream>>>(
      yA, row_ptr2, csr_src, b3, batch, partial);
  post_k<<<N_GRAPHS, 128, 0, stream>>>(partial, batch, wp, bp, out);
}